// Round 6
// baseline (290.202 us; speedup 1.0000x reference)
//
#include <hip/hip_runtime.h>

#define T_STEPS 512
#define BATCH   2048
#define HID     64
#define IN0     8
#define SPB     4               // distinct sequences per block (each replicated x4 in the N=16 tile)
#define NBLK    (BATCH / SPB)   // 512 blocks x 4 waves -> 2 blocks/CU -> 2 waves/SIMD

typedef _Float16 h2 __attribute__((ext_vector_type(2)));
typedef _Float16 h4 __attribute__((ext_vector_type(4)));
typedef _Float16 h8 __attribute__((ext_vector_type(8)));
typedef float    f4 __attribute__((ext_vector_type(4)));

#define MFMA(a, b, c) __builtin_amdgcn_mfma_f32_16x16x32_f16((a), (b), (c), 0, 0, 0)

union F8 { h8 v; h2 p[4]; };
union H4U { h4 v; h2 p[2]; };

__device__ __forceinline__ h2 pkrtz(float a, float b) {
    return __builtin_bit_cast(h2, __builtin_amdgcn_cvt_pkrtz(a, b));
}

// tanh(x) = 1 - 2/(exp(2x)+1); saturates correctly at +/-inf.
__device__ __forceinline__ float tanh_fast(float x) {
    float e = __builtin_amdgcn_exp2f(x * 2.885390081777927f);
    return 1.0f - 2.0f * __builtin_amdgcn_rcpf(e + 1.0f);
}

__global__ __launch_bounds__(256, 2)
void rnn2_mfma(const float* __restrict__ x,
               const float* __restrict__ Wih0, const float* __restrict__ Whh0,
               const float* __restrict__ bih0, const float* __restrict__ bhh0,
               const float* __restrict__ Wih1, const float* __restrict__ Whh1,
               const float* __restrict__ bih1, const float* __restrict__ bhh1,
               const float* __restrict__ fcw,  const float* __restrict__ fcb,
               float* __restrict__ out) {
    const int tid  = threadIdx.x;
    const int w    = tid >> 6;    // wave id = m-tile (H rows 16w..16w+15)
    const int lane = tid & 63;
    const int n    = lane & 15;   // B,C column; sequence = bseq + (n&3) (4x replicated)
    const int q    = lane >> 4;   // quad: k-block for A/B, row-block for C
    const int bseq = blockIdx.x * SPB;

    // H buffers: [n][k] f16, k-stride 72 (+8 pad); double-buffered by t&1
    __shared__ __align__(16) _Float16 H0b[2][16 * 72];
    __shared__ __align__(16) _Float16 H1b[2][16 * 72];
    __shared__ float red[4][16];

    // ---- resident A-fragments for rows 16w+n: slot j <-> k = 32kt+8q+j ----
    h8 wh0[2], wi1[2], wh1[2];
    const int row = 16 * w + n;
    #pragma unroll
    for (int kt = 0; kt < 2; ++kt) {
        const int k0 = 32 * kt + 8 * q;
        {
            const float4* p = (const float4*)(Whh0 + row * HID + k0);
            float4 a = p[0], b = p[1];
            F8 f; f.p[0] = pkrtz(a.x, a.y); f.p[1] = pkrtz(a.z, a.w);
                  f.p[2] = pkrtz(b.x, b.y); f.p[3] = pkrtz(b.z, b.w);
            wh0[kt] = f.v;
        }
        {
            const float4* p = (const float4*)(Wih1 + row * HID + k0);
            float4 a = p[0], b = p[1];
            F8 f; f.p[0] = pkrtz(a.x, a.y); f.p[1] = pkrtz(a.z, a.w);
                  f.p[2] = pkrtz(b.x, b.y); f.p[3] = pkrtz(b.z, b.w);
            wi1[kt] = f.v;
        }
        {
            const float4* p = (const float4*)(Whh1 + row * HID + k0);
            float4 a = p[0], b = p[1];
            F8 f; f.p[0] = pkrtz(a.x, a.y); f.p[1] = pkrtz(a.z, a.w);
                  f.p[2] = pkrtz(b.x, b.y); f.p[3] = pkrtz(b.z, b.w);
            wh1[kt] = f.v;
        }
    }
    // Wih0 (64x8), K zero-padded; slot 0 holds k=2q,2q+1 (X B-frag matches)
    h8 wi0;
    {
        const float2 ww = *(const float2*)(Wih0 + row * IN0 + 2 * q);
        F8 f; f.p[0] = pkrtz(ww.x, ww.y);
        f.p[1] = pkrtz(0.f, 0.f); f.p[2] = f.p[1]; f.p[3] = f.p[1];
        wi0 = f.v;
    }
    // biases / fc weights in C-layout: reg r <-> row 16w + 4q + r
    f4 bias0, bias1, fcv;
    #pragma unroll
    for (int r = 0; r < 4; ++r) {
        const int i = 16 * w + 4 * q + r;
        bias0[r] = bih0[i] + bhh0[i];
        bias1[r] = bih1[i] + bhh1[i];
        fcv[r]   = fcw[i];
    }
    const float fcb0 = fcb[0];
    const f4 zero = {0.f, 0.f, 0.f, 0.f};

    // x: lane (q,n) streams x[bseq+(n&3)][t][2q..2q+1] (columns replicated x4)
    const float* xp = x + ((size_t)(bseq + (n & (SPB - 1))) * T_STEPS) * IN0 + 2 * q;
    float2 xc = *(const float2*)xp;

    h8 h0f[2] = {}; h8 h1f[2] = {};   // H0_{t-1}, H1_{t-2} B-frags (start 0)

    // hoisted Wih0@x_0 + bias0
    f4 a0x;
    {
        F8 xf; xf.p[0] = pkrtz(xc.x, xc.y);
        xf.p[1] = pkrtz(0.f, 0.f); xf.p[2] = xf.p[1]; xf.p[3] = xf.p[1];
        a0x = MFMA(wi0, xf.v, bias0);
    }

    #pragma unroll 2
    for (int t = 0; t < T_STEPS; ++t) {
        const int tn = (t + 1 < T_STEPS) ? t + 1 : t;
        const float2 xnx = *(const float2*)(xp + tn * IN0);
        const int bf = t & 1;

        // ---- layer0(t): a0 = (a0x) + Whh0@H0_{t-1}; a0x folded as C-init ----
        f4 a0 = MFMA(wh0[0], h0f[0], a0x);
        a0    = MFMA(wh0[1], h0f[1], a0);

        // ---- layer1(t-1): a1 = b1 + Wih1@H0_{t-1} + Whh1@H1_{t-2} ----
        f4 c1 = MFMA(wi1[0], h0f[0], bias1);
        c1    = MFMA(wi1[1], h0f[1], c1);
        f4 c2 = MFMA(wh1[0], h1f[0], zero);
        c2    = MFMA(wh1[1], h1f[1], c2);

        // H0_t = tanh(a0) -> LDS
        {
            H4U u;
            u.p[0] = pkrtz(tanh_fast(a0[0]), tanh_fast(a0[1]));
            u.p[1] = pkrtz(tanh_fast(a0[2]), tanh_fast(a0[3]));
            *(h4*)&H0b[bf][n * 72 + w * 16 + q * 4] = u.v;   // k = 16w+4q+(0..3)
        }
        // H1_{t-1} = tanh(a1) -> LDS (t=0: true H1_{-1}=0)
        {
            const f4 a1 = c1 + c2;
            H4U u;
            u.p[0] = pkrtz(tanh_fast(a1[0]), tanh_fast(a1[1]));
            u.p[1] = pkrtz(tanh_fast(a1[2]), tanh_fast(a1[3]));
            if (t == 0) { u.p[0] = pkrtz(0.f, 0.f); u.p[1] = u.p[0]; }
            *(h4*)&H1b[bf][n * 72 + w * 16 + q * 4] = u.v;
        }

        // hoisted Wih0@x_{t+1} + bias0 (independent of the barrier)
        {
            F8 xf; xf.p[0] = pkrtz(xnx.x, xnx.y);
            xf.p[1] = pkrtz(0.f, 0.f); xf.p[2] = xf.p[1]; xf.p[3] = xf.p[1];
            a0x = MFMA(wi0, xf.v, bias0);
        }
        xc = xnx;

        __syncthreads();

        #pragma unroll
        for (int kt = 0; kt < 2; ++kt) {
            h0f[kt] = *(const h8*)&H0b[bf][n * 72 + kt * 32 + q * 8];
            h1f[kt] = *(const h8*)&H1b[bf][n * 72 + kt * 32 + q * 8];
        }
    }

    // ---- epilogue: layer1(T-1) from h0f=H0_{511}, h1f=H1_{510} ----
    f4 c1 = MFMA(wi1[0], h0f[0], bias1);
    c1    = MFMA(wi1[1], h0f[1], c1);
    f4 c2 = MFMA(wh1[0], h1f[0], zero);
    c2    = MFMA(wh1[1], h1f[1], c2);
    const f4 a1 = c1 + c2;

    // FC head: per-lane dot over its 4 rows, reduce q, then cross-wave
    float s = 0.f;
    #pragma unroll
    for (int r = 0; r < 4; ++r) s += fcv[r] * tanh_fast(a1[r]);
    s += __shfl_xor(s, 16, 64);
    s += __shfl_xor(s, 32, 64);
    if (lane < 16) red[w][n] = s;    // q==0 lanes
    __syncthreads();
    if (tid < SPB)
        out[bseq + tid] = red[0][tid] + red[1][tid] + red[2][tid] + red[3][tid] + fcb0;
}

extern "C" void kernel_launch(void* const* d_in, const int* in_sizes, int n_in,
                              void* d_out, int out_size, void* d_ws, size_t ws_size,
                              hipStream_t stream) {
    const float* x    = (const float*)d_in[0];
    const float* Wih0 = (const float*)d_in[1];
    const float* Whh0 = (const float*)d_in[2];
    const float* bih0 = (const float*)d_in[3];
    const float* bhh0 = (const float*)d_in[4];
    const float* Wih1 = (const float*)d_in[5];
    const float* Whh1 = (const float*)d_in[6];
    const float* bih1 = (const float*)d_in[7];
    const float* bhh1 = (const float*)d_in[8];
    const float* fcw  = (const float*)d_in[9];
    const float* fcb  = (const float*)d_in[10];
    float* out = (float*)d_out;

    rnn2_mfma<<<dim3(NBLK), dim3(256), 0, stream>>>(
        x, Wih0, Whh0, bih0, bhh0, Wih1, Whh1, bih1, bhh1, fcw, fcb, out);
}

// Round 7
// 283.060 us; speedup vs baseline: 1.0252x; 1.0252x over previous
//
#include <hip/hip_runtime.h>

#define T_STEPS 512
#define BATCH   2048
#define HID     64
#define IN0     8
#define SPB     4               // distinct sequences per block (replicated x4 in the N=16 tile)
#define NBLK    (BATCH / SPB)   // 512 blocks x 4 waves -> 2 blocks/CU -> 2 waves/SIMD

typedef _Float16 h2 __attribute__((ext_vector_type(2)));
typedef _Float16 h4 __attribute__((ext_vector_type(4)));
typedef _Float16 h8 __attribute__((ext_vector_type(8)));
typedef float    f4 __attribute__((ext_vector_type(4)));

#define MFMA(a, b, c) __builtin_amdgcn_mfma_f32_16x16x32_f16((a), (b), (c), 0, 0, 0)

union F8 { h8 v; h2 p[4]; };
union H4U { h4 v; h2 p[2]; };

__device__ __forceinline__ h2 pkrtz(float a, float b) {
    return __builtin_bit_cast(h2, __builtin_amdgcn_cvt_pkrtz(a, b));
}

// tanh(x) = 1 - 2/(exp(2x)+1); saturates correctly at +/-inf.
__device__ __forceinline__ float tanh_fast(float x) {
    float e = __builtin_amdgcn_exp2f(x * 2.885390081777927f);
    return 1.0f - 2.0f * __builtin_amdgcn_rcpf(e + 1.0f);
}

__global__ __launch_bounds__(256, 2)
void rnn2_mfma(const float* __restrict__ x,
               const float* __restrict__ Wih0, const float* __restrict__ Whh0,
               const float* __restrict__ bih0, const float* __restrict__ bhh0,
               const float* __restrict__ Wih1, const float* __restrict__ Whh1,
               const float* __restrict__ bih1, const float* __restrict__ bhh1,
               const float* __restrict__ fcw,  const float* __restrict__ fcb,
               float* __restrict__ out) {
    const int tid  = threadIdx.x;
    const int w    = tid >> 6;    // wave id = m-tile (H rows 16w..16w+15)
    const int lane = tid & 63;
    const int n    = lane & 15;   // B,C column; sequence = bseq + (n&3) (4x replicated)
    const int q    = lane >> 4;   // quad: k-block for A/B, row-block for C
    const int m    = n & 3;       // distinct sequence id within block
    const int bseq = blockIdx.x * SPB;

    // Deduped H: only 4 distinct rows (seqs) x 64 k, f16, XOR-16-block swizzled:
    // element (row m, k=16B+o) lives at m*64 + 16*(B^m) + o.
    // Writes (lanes n<4) are exactly conflict-free; reads are 4-lane broadcasts.
    __shared__ __align__(16) _Float16 H0b[2][SPB * HID];
    __shared__ __align__(16) _Float16 H1b[2][SPB * HID];
    __shared__ float red[4][16];

    // write index (valid for n<4): row n, k-block B=w, offset 4q
    const int widx = n * HID + 16 * (w ^ n) + 4 * q;
    // read indices: kt=0 -> B=(q>>1); kt=1 -> B=2+(q>>1); offset 8*(q&1)
    const int ridx0 = m * HID + 16 * (((q >> 1) + 0) ^ m) + 8 * (q & 1);
    const int ridx1 = m * HID + 16 * (((q >> 1) + 2) ^ m) + 8 * (q & 1);

    // ---- resident A-fragments for rows 16w+n: slot j <-> k = 32kt+8q+j ----
    h8 wh0[2], wi1[2], wh1[2];
    const int row = 16 * w + n;
    #pragma unroll
    for (int kt = 0; kt < 2; ++kt) {
        const int k0 = 32 * kt + 8 * q;
        {
            const float4* p = (const float4*)(Whh0 + row * HID + k0);
            float4 a = p[0], b = p[1];
            F8 f; f.p[0] = pkrtz(a.x, a.y); f.p[1] = pkrtz(a.z, a.w);
                  f.p[2] = pkrtz(b.x, b.y); f.p[3] = pkrtz(b.z, b.w);
            wh0[kt] = f.v;
        }
        {
            const float4* p = (const float4*)(Wih1 + row * HID + k0);
            float4 a = p[0], b = p[1];
            F8 f; f.p[0] = pkrtz(a.x, a.y); f.p[1] = pkrtz(a.z, a.w);
                  f.p[2] = pkrtz(b.x, b.y); f.p[3] = pkrtz(b.z, b.w);
            wi1[kt] = f.v;
        }
        {
            const float4* p = (const float4*)(Whh1 + row * HID + k0);
            float4 a = p[0], b = p[1];
            F8 f; f.p[0] = pkrtz(a.x, a.y); f.p[1] = pkrtz(a.z, a.w);
                  f.p[2] = pkrtz(b.x, b.y); f.p[3] = pkrtz(b.z, b.w);
            wh1[kt] = f.v;
        }
    }
    // Wih0 (64x8), K zero-padded; slot 0 holds k=2q,2q+1 (X B-frag matches)
    h8 wi0;
    {
        const float2 ww = *(const float2*)(Wih0 + row * IN0 + 2 * q);
        F8 f; f.p[0] = pkrtz(ww.x, ww.y);
        f.p[1] = pkrtz(0.f, 0.f); f.p[2] = f.p[1]; f.p[3] = f.p[1];
        wi0 = f.v;
    }
    // biases / fc weights in C-layout: reg r <-> row 16w + 4q + r
    f4 bias0, bias1, fcv;
    #pragma unroll
    for (int r = 0; r < 4; ++r) {
        const int i = 16 * w + 4 * q + r;
        bias0[r] = bih0[i] + bhh0[i];
        bias1[r] = bih1[i] + bhh1[i];
        fcv[r]   = fcw[i];
    }
    const float fcb0 = fcb[0];
    const f4 zero = {0.f, 0.f, 0.f, 0.f};

    // x: lane (q,n) streams x[bseq+m][t][2q..2q+1] (columns replicated x4)
    const float* xp = x + ((size_t)(bseq + m) * T_STEPS) * IN0 + 2 * q;
    float2 xc = *(const float2*)xp;

    h8 h0f[2] = {}; h8 h1f[2] = {};   // H0_{t-1}, H1_{t-2} B-frags (start 0)

    // hoisted Wih0@x_0 + bias0
    f4 a0x;
    {
        F8 xf; xf.p[0] = pkrtz(xc.x, xc.y);
        xf.p[1] = pkrtz(0.f, 0.f); xf.p[2] = xf.p[1]; xf.p[3] = xf.p[1];
        a0x = MFMA(wi0, xf.v, bias0);
    }

    #pragma unroll 2
    for (int t = 0; t < T_STEPS; ++t) {
        const int tn = (t + 1 < T_STEPS) ? t + 1 : t;
        const float2 xnx = *(const float2*)(xp + tn * IN0);
        const int bf = t & 1;

        // ---- layer0(t): a0 = (a0x) + Whh0@H0_{t-1}; a0x folded as C-init ----
        f4 a0 = MFMA(wh0[0], h0f[0], a0x);
        a0    = MFMA(wh0[1], h0f[1], a0);

        // ---- layer1(t-1): a1 = b1 + Wih1@H0_{t-1} + Whh1@H1_{t-2} ----
        f4 c1 = MFMA(wi1[0], h0f[0], bias1);
        c1    = MFMA(wi1[1], h0f[1], c1);
        f4 c2 = MFMA(wh1[0], h1f[0], zero);
        c2    = MFMA(wh1[1], h1f[1], c2);

        // H0_t = tanh(a0); H1_{t-1} = tanh(a1); only n<4 lanes publish
        H4U u0;
        u0.p[0] = pkrtz(tanh_fast(a0[0]), tanh_fast(a0[1]));
        u0.p[1] = pkrtz(tanh_fast(a0[2]), tanh_fast(a0[3]));
        const f4 a1 = c1 + c2;
        H4U u1;
        u1.p[0] = pkrtz(tanh_fast(a1[0]), tanh_fast(a1[1]));
        u1.p[1] = pkrtz(tanh_fast(a1[2]), tanh_fast(a1[3]));
        if (t == 0) { u1.p[0] = pkrtz(0.f, 0.f); u1.p[1] = u1.p[0]; }  // true H1_{-1}=0
        if (n < SPB) {
            *(h4*)&H0b[bf][widx] = u0.v;
            *(h4*)&H1b[bf][widx] = u1.v;
        }

        // hoisted Wih0@x_{t+1} + bias0 (independent of the barrier)
        {
            F8 xf; xf.p[0] = pkrtz(xnx.x, xnx.y);
            xf.p[1] = pkrtz(0.f, 0.f); xf.p[2] = xf.p[1]; xf.p[3] = xf.p[1];
            a0x = MFMA(wi0, xf.v, bias0);
        }
        xc = xnx;

        __syncthreads();

        h0f[0] = *(const h8*)&H0b[bf][ridx0];
        h0f[1] = *(const h8*)&H0b[bf][ridx1];
        h1f[0] = *(const h8*)&H1b[bf][ridx0];
        h1f[1] = *(const h8*)&H1b[bf][ridx1];
    }

    // ---- epilogue: layer1(T-1) from h0f=H0_{511}, h1f=H1_{510} ----
    f4 c1 = MFMA(wi1[0], h0f[0], bias1);
    c1    = MFMA(wi1[1], h0f[1], c1);
    f4 c2 = MFMA(wh1[0], h1f[0], zero);
    c2    = MFMA(wh1[1], h1f[1], c2);
    const f4 a1 = c1 + c2;

    // FC head: per-lane dot over its 4 rows, reduce q, then cross-wave
    float s = 0.f;
    #pragma unroll
    for (int r = 0; r < 4; ++r) s += fcv[r] * tanh_fast(a1[r]);
    s += __shfl_xor(s, 16, 64);
    s += __shfl_xor(s, 32, 64);
    if (lane < 16) red[w][n] = s;    // q==0 lanes
    __syncthreads();
    if (tid < SPB)
        out[bseq + tid] = red[0][tid] + red[1][tid] + red[2][tid] + red[3][tid] + fcb0;
}

extern "C" void kernel_launch(void* const* d_in, const int* in_sizes, int n_in,
                              void* d_out, int out_size, void* d_ws, size_t ws_size,
                              hipStream_t stream) {
    const float* x    = (const float*)d_in[0];
    const float* Wih0 = (const float*)d_in[1];
    const float* Whh0 = (const float*)d_in[2];
    const float* bih0 = (const float*)d_in[3];
    const float* bhh0 = (const float*)d_in[4];
    const float* Wih1 = (const float*)d_in[5];
    const float* Whh1 = (const float*)d_in[6];
    const float* bih1 = (const float*)d_in[7];
    const float* bhh1 = (const float*)d_in[8];
    const float* fcw  = (const float*)d_in[9];
    const float* fcb  = (const float*)d_in[10];
    float* out = (float*)d_out;

    rnn2_mfma<<<dim3(NBLK), dim3(256), 0, stream>>>(
        x, Wih0, Whh0, bih0, bhh0, Wih1, Whh1, bih1, bhh1, fcw, fcb, out);
}